// Round 6
// baseline (889.501 us; speedup 1.0000x reference)
//
#include <hip/hip_runtime.h>

#define BN_EPS 1e-5f

using bf16x8 = __attribute__((ext_vector_type(8))) short;
using f32x4  = __attribute__((ext_vector_type(4))) float;

__device__ __forceinline__ unsigned int f2bf(float f) {   // RTNE fp32->bf16
    unsigned int u = __float_as_uint(f);
    u += 0x7fffu + ((u >> 16) & 1u);
    return u >> 16;
}
__device__ __forceinline__ float bflo(unsigned int u) { return __uint_as_float(u << 16); }
__device__ __forceinline__ float bfhi(unsigned int u) { return __uint_as_float(u & 0xffff0000u); }

// ================= CSR build: two-phase counting sort by dst ================
// bucket b = dst >> 8 (256 nodes/bucket), NB <= 768. 8192 edges per block.

__global__ __launch_bounds__(256) void k_bhist(const int* __restrict__ ei,
                                               int* __restrict__ bcnt, int E, int NB) {
    __shared__ int h[768];
    for (int i = threadIdx.x; i < 768; i += 256) h[i] = 0;
    __syncthreads();
    int base = blockIdx.x * 8192;
    #pragma unroll
    for (int it = 0; it < 32; ++it) {
        int e = base + it * 256 + threadIdx.x;
        if (e < E) atomicAdd(&h[ei[E + e] >> 8], 1);
    }
    __syncthreads();
    for (int i = threadIdx.x; i < NB; i += 256)
        if (h[i]) atomicAdd(&bcnt[i], h[i]);
}

// exclusive scan of bucket counts -> bbase[0..NB], cursor copy
__global__ __launch_bounds__(1024) void k_bscan(const int* __restrict__ bcnt,
                                                int* __restrict__ bbase,
                                                int* __restrict__ bcur, int NB) {
    __shared__ int s[1024];
    int v = (threadIdx.x < NB) ? bcnt[threadIdx.x] : 0;
    s[threadIdx.x] = v;
    __syncthreads();
    for (int off = 1; off < 1024; off <<= 1) {
        int t = (threadIdx.x >= off) ? s[threadIdx.x - off] : 0;
        __syncthreads();
        s[threadIdx.x] += t;
        __syncthreads();
    }
    if (threadIdx.x < NB) {
        int ex = s[threadIdx.x] - v;
        bbase[threadIdx.x] = ex;
        bcur[threadIdx.x]  = ex;
    }
    if (threadIdx.x == 1023) bbase[NB] = s[1023];
}

// scatter packed (src | (dst&255)<<24) into bucket-sorted ebuf
__global__ __launch_bounds__(256) void k_bscatter(const int* __restrict__ ei,
                                                  int* __restrict__ bcur,
                                                  unsigned int* __restrict__ ebuf,
                                                  int E, int NB) {
    __shared__ int h[768];
    __shared__ int wb[768];
    for (int i = threadIdx.x; i < 768; i += 256) h[i] = 0;
    __syncthreads();
    int base = blockIdx.x * 8192;
    int rk[32];
    #pragma unroll
    for (int it = 0; it < 32; ++it) {
        int e = base + it * 256 + threadIdx.x;
        rk[it] = (e < E) ? atomicAdd(&h[ei[E + e] >> 8], 1) : 0;
    }
    __syncthreads();
    for (int i = threadIdx.x; i < NB; i += 256) {
        int c = h[i];
        wb[i] = c ? atomicAdd(&bcur[i], c) : 0;
    }
    __syncthreads();
    #pragma unroll
    for (int it = 0; it < 32; ++it) {
        int e = base + it * 256 + threadIdx.x;
        if (e < E) {
            unsigned s = (unsigned)ei[e], d = (unsigned)ei[E + e];
            ebuf[wb[d >> 8] + rk[it]] = s | ((d & 255u) << 24);
        }
    }
}

// per-bucket node counts -> rs (coalesced), dinv fused
__global__ __launch_bounds__(256) void k_bcount(const unsigned int* __restrict__ ebuf,
                                                const int* __restrict__ bbase,
                                                int* __restrict__ rs,
                                                float* __restrict__ dinv, int N) {
    __shared__ int cnt[256];
    cnt[threadIdx.x] = 0;
    __syncthreads();
    int b = blockIdx.x;
    int beg = bbase[b], end = bbase[b + 1];
    for (int j = beg + threadIdx.x; j < end; j += 256)
        atomicAdd(&cnt[ebuf[j] >> 24], 1);
    __syncthreads();
    int node = b * 256 + threadIdx.x;
    if (node < N) {
        int c = cnt[threadIdx.x];
        rs[node]   = c;
        dinv[node] = rsqrtf((float)(1 + c));   // +1 self-loop
    }
}

// exclusive scan over rs[0..N-1]
__global__ __launch_bounds__(256) void k_scan_part(int* __restrict__ rs,
                                                   int* __restrict__ bsum, int N) {
    __shared__ int s[256];
    int i = blockIdx.x * 256 + threadIdx.x;
    int v = (i < N) ? rs[i] : 0;
    s[threadIdx.x] = v;
    __syncthreads();
    for (int off = 1; off < 256; off <<= 1) {
        int t = (threadIdx.x >= off) ? s[threadIdx.x - off] : 0;
        __syncthreads();
        s[threadIdx.x] += t;
        __syncthreads();
    }
    if (i < N) rs[i] = s[threadIdx.x] - v;
    if (threadIdx.x == 255) bsum[blockIdx.x] = s[255];
}

__global__ __launch_bounds__(1024) void k_scan_sums(int* __restrict__ bsum, int nb) {
    __shared__ int s[1024];
    int v = (threadIdx.x < nb) ? bsum[threadIdx.x] : 0;
    s[threadIdx.x] = v;
    __syncthreads();
    for (int off = 1; off < 1024; off <<= 1) {
        int t = (threadIdx.x >= off) ? s[threadIdx.x - off] : 0;
        __syncthreads();
        s[threadIdx.x] += t;
        __syncthreads();
    }
    if (threadIdx.x < nb) bsum[threadIdx.x] = s[threadIdx.x] - v;
}

__global__ __launch_bounds__(256) void k_scan_add(int* __restrict__ rs,
                                                  const int* __restrict__ bsum, int N) {
    int i = blockIdx.x * 256 + threadIdx.x;
    if (i < N) rs[i] += bsum[blockIdx.x];
}

// place srcs into csr via LDS node cursors (writes stay in-bucket)
__global__ __launch_bounds__(256) void k_bplace(const unsigned int* __restrict__ ebuf,
                                                const int* __restrict__ bbase,
                                                const int* __restrict__ rs,
                                                int* __restrict__ csr, int N) {
    __shared__ int cur[256];
    int b = blockIdx.x;
    int node = b * 256 + threadIdx.x;
    cur[threadIdx.x] = (node < N) ? rs[node] : 0;
    __syncthreads();
    int beg = bbase[b], end = bbase[b + 1];
    for (int j = beg + threadIdx.x; j < end; j += 256) {
        unsigned e = ebuf[j];
        int pos = atomicAdd(&cur[e >> 24], 1);
        csr[pos] = (int)(e & 0x00FFFFFFu);
    }
}

// ==================== weight prep: bf16 B-fragment order ====================
__global__ __launch_bounds__(256) void k_prepW(const float* __restrict__ W,
                                               unsigned short* __restrict__ Wf, int C) {
    int t = blockIdx.x * 256 + threadIdx.x;
    if (t >= 2048) return;
    int lane = t & 63, frag = t >> 6;
    int kt = frag & 3, ct = frag >> 2;
    int r = lane & 15, q = lane >> 4;
    int col = ct * 16 + r;
    int kbase = kt * 32 + q * 8;
    unsigned int v[8];
    #pragma unroll
    for (int j = 0; j < 8; ++j)
        v[j] = (col < C) ? f2bf(W[(size_t)(kbase + j) * C + col]) : 0u;
    uint4 o;
    o.x = v[0] | (v[1] << 16);
    o.y = v[2] | (v[3] << 16);
    o.z = v[4] | (v[5] << 16);
    o.w = v[6] | (v[7] << 16);
    ((uint4*)Wf)[t] = o;
}

// ============================== MFMA GEMM ===================================
__device__ __forceinline__ float bn_apply(float v, int c, const float* stats,
                                          const float* g, const float* be, float invN) {
    float mean = stats[c] * invN;
    float var  = fmaf(-mean, mean, stats[128 + c] * invN);
    float sc   = g[c] * rsqrtf(var + BN_EPS);
    float r    = fmaf(v - mean, sc, be[c]);
    return fmaxf(r, 0.0f);
}

// H_bf16[N,128] = bf16( bn_relu(X) @ W ).  X is f32 (xf32=1) or bf16 (xf32=0).
__global__ __launch_bounds__(256) void k_gemm_mfma(
        const void* __restrict__ X, int xf32, const unsigned short* __restrict__ Wf,
        unsigned short* __restrict__ H, int N,
        const float* __restrict__ stats, const float* __restrict__ g,
        const float* __restrict__ be) {
    __shared__ unsigned short aF[16 * 512];   // 16 KB, A frags
    __shared__ unsigned short bF[32 * 512];   // 32 KB, B frags
    const int tid = threadIdx.x;
    const int rowbase = blockIdx.x * 64;
    const float invN = 1.0f / (float)N;

    {   // stage B
        const uint4* src = (const uint4*)Wf;
        uint4* dst = (uint4*)bF;
        #pragma unroll
        for (int i = 0; i < 8; ++i) dst[tid + 256 * i] = src[tid + 256 * i];
    }
    // stage A: one frag-slot per task, BN+ReLU fused
    #pragma unroll
    for (int it = 0; it < 4; ++it) {
        int f = tid + 256 * it;
        int lane = f & 63, frag = f >> 6;
        int kt = frag & 3, rt = frag >> 2;
        int r = lane & 15, q = lane >> 4;
        int row = rowbase + rt * 16 + r;
        int kc = kt * 32 + q * 8;
        float vv[8];
        if (row < N) {
            if (xf32) {
                const float4* xp = (const float4*)((const float*)X + (size_t)row * 128 + kc);
                float4 p0 = xp[0], p1 = xp[1];
                vv[0] = p0.x; vv[1] = p0.y; vv[2] = p0.z; vv[3] = p0.w;
                vv[4] = p1.x; vv[5] = p1.y; vv[6] = p1.z; vv[7] = p1.w;
            } else {
                uint4 p = *((const uint4*)((const unsigned short*)X + (size_t)row * 128 + kc));
                vv[0] = bflo(p.x); vv[1] = bfhi(p.x);
                vv[2] = bflo(p.y); vv[3] = bfhi(p.y);
                vv[4] = bflo(p.z); vv[5] = bfhi(p.z);
                vv[6] = bflo(p.w); vv[7] = bfhi(p.w);
            }
            if (stats) {
                #pragma unroll
                for (int j = 0; j < 8; ++j)
                    vv[j] = bn_apply(vv[j], kc + j, stats, g, be, invN);
            }
        } else {
            #pragma unroll
            for (int j = 0; j < 8; ++j) vv[j] = 0.0f;
        }
        uint4 o;
        o.x = f2bf(vv[0]) | (f2bf(vv[1]) << 16);
        o.y = f2bf(vv[2]) | (f2bf(vv[3]) << 16);
        o.z = f2bf(vv[4]) | (f2bf(vv[5]) << 16);
        o.w = f2bf(vv[6]) | (f2bf(vv[7]) << 16);
        ((uint4*)aF)[f] = o;
    }
    __syncthreads();

    const int wave = tid >> 6, lane = tid & 63;
    f32x4 acc[8];
    #pragma unroll
    for (int ct = 0; ct < 8; ++ct) acc[ct] = (f32x4){0.f, 0.f, 0.f, 0.f};

    #pragma unroll
    for (int kt = 0; kt < 4; ++kt) {
        bf16x8 a = ((const bf16x8*)aF)[(wave * 4 + kt) * 64 + lane];
        #pragma unroll
        for (int ct = 0; ct < 8; ++ct) {
            bf16x8 b = ((const bf16x8*)bF)[(ct * 4 + kt) * 64 + lane];
            acc[ct] = __builtin_amdgcn_mfma_f32_16x16x32_bf16(a, b, acc[ct], 0, 0, 0);
        }
    }

    const int q = lane >> 4, r = lane & 15;   // C/D: col=lane&15, row=q*4+reg
    #pragma unroll
    for (int ct = 0; ct < 8; ++ct) {
        #pragma unroll
        for (int i = 0; i < 4; ++i) {
            int row = rowbase + wave * 16 + q * 4 + i;
            if (row < N)
                H[(size_t)row * 128 + ct * 16 + r] = (unsigned short)f2bf(acc[ct][i]);
        }
    }
}

// ========================= gather aggregate + BN stats ======================
// out_bf16[d] = b + H[d]*dinv[d]^2 + sum_s H[s]*dinv[s]*dinv[d]
// Also accumulates per-channel sum/sumsq into pstats[64 slots][256].
__global__ __launch_bounds__(256) void k_agg128(
        const unsigned short* __restrict__ H, const int* __restrict__ rs,
        const int* __restrict__ csr_src, const float* __restrict__ dinv,
        const float* __restrict__ b, unsigned short* __restrict__ outb,
        float* __restrict__ pstats, int N, int E) {
    __shared__ float ssum[128];
    __shared__ float ssq[128];
    const int tid = threadIdx.x;
    if (tid < 128) { ssum[tid] = 0.f; ssq[tid] = 0.f; }
    __syncthreads();

    int lane = tid & 31;
    int node = blockIdx.x * 8 + (tid >> 5);
    float4 acc = make_float4(0.f, 0.f, 0.f, 0.f);
    bool active = (node < N);
    if (active) {
        float dd  = dinv[node];
        int   beg = rs[node];
        int   end = (node == N - 1) ? E : rs[node + 1];
        uint2 hp  = ((const uint2*)(H + (size_t)node * 128))[lane];
        float4 bb = ((const float4*)b)[lane];
        float  sl = dd * dd;
        acc = make_float4(fmaf(bflo(hp.x), sl, bb.x), fmaf(bfhi(hp.x), sl, bb.y),
                          fmaf(bflo(hp.y), sl, bb.z), fmaf(bfhi(hp.y), sl, bb.w));
        int j = beg;
        for (; j + 4 <= end; j += 4) {
            int s0 = csr_src[j], s1 = csr_src[j + 1];
            int s2 = csr_src[j + 2], s3 = csr_src[j + 3];
            float n0 = dinv[s0] * dd, n1 = dinv[s1] * dd;
            float n2 = dinv[s2] * dd, n3 = dinv[s3] * dd;
            uint2 v0 = ((const uint2*)(H + (size_t)s0 * 128))[lane];
            uint2 v1 = ((const uint2*)(H + (size_t)s1 * 128))[lane];
            uint2 v2 = ((const uint2*)(H + (size_t)s2 * 128))[lane];
            uint2 v3 = ((const uint2*)(H + (size_t)s3 * 128))[lane];
            acc.x = fmaf(bflo(v0.x), n0, fmaf(bflo(v1.x), n1,
                    fmaf(bflo(v2.x), n2, fmaf(bflo(v3.x), n3, acc.x))));
            acc.y = fmaf(bfhi(v0.x), n0, fmaf(bfhi(v1.x), n1,
                    fmaf(bfhi(v2.x), n2, fmaf(bfhi(v3.x), n3, acc.y))));
            acc.z = fmaf(bflo(v0.y), n0, fmaf(bflo(v1.y), n1,
                    fmaf(bflo(v2.y), n2, fmaf(bflo(v3.y), n3, acc.z))));
            acc.w = fmaf(bfhi(v0.y), n0, fmaf(bfhi(v1.y), n1,
                    fmaf(bfhi(v2.y), n2, fmaf(bfhi(v3.y), n3, acc.w))));
        }
        for (; j < end; ++j) {
            int s0 = csr_src[j];
            float n0 = dinv[s0] * dd;
            uint2 v0 = ((const uint2*)(H + (size_t)s0 * 128))[lane];
            acc.x = fmaf(bflo(v0.x), n0, acc.x);
            acc.y = fmaf(bfhi(v0.x), n0, acc.y);
            acc.z = fmaf(bflo(v0.y), n0, acc.z);
            acc.w = fmaf(bfhi(v0.y), n0, acc.w);
        }
        uint2 o;
        o.x = f2bf(acc.x) | (f2bf(acc.y) << 16);
        o.y = f2bf(acc.z) | (f2bf(acc.w) << 16);
        ((uint2*)(outb + (size_t)node * 128))[lane] = o;

        int c = lane * 4;
        atomicAdd(&ssum[c + 0], acc.x); atomicAdd(&ssq[c + 0], acc.x * acc.x);
        atomicAdd(&ssum[c + 1], acc.y); atomicAdd(&ssq[c + 1], acc.y * acc.y);
        atomicAdd(&ssum[c + 2], acc.z); atomicAdd(&ssq[c + 2], acc.z * acc.z);
        atomicAdd(&ssum[c + 3], acc.w); atomicAdd(&ssq[c + 3], acc.w * acc.w);
    }
    __syncthreads();
    if (tid < 128) {
        float* slot = pstats + (size_t)(blockIdx.x & 63) * 256;
        unsafeAtomicAdd(&slot[tid], ssum[tid]);
        unsafeAtomicAdd(&slot[128 + tid], ssq[tid]);
    }
}

// reduce 64 partial slots -> stats[256]
__global__ __launch_bounds__(256) void k_statreduce(const float* __restrict__ p,
                                                    float* __restrict__ stats) {
    int t = threadIdx.x;
    float s = 0.f;
    #pragma unroll 8
    for (int k = 0; k < 64; ++k) s += p[k * 256 + t];
    stats[t] = s;
}

// 40-ch final: f32 output
__global__ __launch_bounds__(256) void k_agg40(
        const unsigned short* __restrict__ H, const int* __restrict__ rs,
        const int* __restrict__ csr_src, const float* __restrict__ dinv,
        const float* __restrict__ b, float* __restrict__ out, int N, int E) {
    int lane = threadIdx.x & 15;
    int node = blockIdx.x * 16 + (threadIdx.x >> 4);
    if (node >= N || lane >= 10) return;
    float dd  = dinv[node];
    int   beg = rs[node];
    int   end = (node == N - 1) ? E : rs[node + 1];
    uint2 hp  = ((const uint2*)(H + (size_t)node * 128))[lane];
    float4 bb = ((const float4*)b)[lane];
    float  sl = dd * dd;
    float4 acc = make_float4(fmaf(bflo(hp.x), sl, bb.x), fmaf(bfhi(hp.x), sl, bb.y),
                             fmaf(bflo(hp.y), sl, bb.z), fmaf(bfhi(hp.y), sl, bb.w));
    int j = beg;
    for (; j + 2 <= end; j += 2) {
        int s0 = csr_src[j], s1 = csr_src[j + 1];
        float n0 = dinv[s0] * dd, n1 = dinv[s1] * dd;
        uint2 v0 = ((const uint2*)(H + (size_t)s0 * 128))[lane];
        uint2 v1 = ((const uint2*)(H + (size_t)s1 * 128))[lane];
        acc.x = fmaf(bflo(v0.x), n0, fmaf(bflo(v1.x), n1, acc.x));
        acc.y = fmaf(bfhi(v0.x), n0, fmaf(bfhi(v1.x), n1, acc.y));
        acc.z = fmaf(bflo(v0.y), n0, fmaf(bflo(v1.y), n1, acc.z));
        acc.w = fmaf(bfhi(v0.y), n0, fmaf(bfhi(v1.y), n1, acc.w));
    }
    if (j < end) {
        int s0 = csr_src[j];
        float n0 = dinv[s0] * dd;
        uint2 v0 = ((const uint2*)(H + (size_t)s0 * 128))[lane];
        acc.x = fmaf(bflo(v0.x), n0, acc.x);
        acc.y = fmaf(bfhi(v0.x), n0, acc.y);
        acc.z = fmaf(bflo(v0.y), n0, acc.z);
        acc.w = fmaf(bfhi(v0.y), n0, acc.w);
    }
    ((float4*)(out + (size_t)node * 40))[lane] = acc;
}

// ================================ launch ====================================
extern "C" void kernel_launch(void* const* d_in, const int* in_sizes, int n_in,
                              void* d_out, int out_size, void* d_ws, size_t ws_size,
                              hipStream_t stream) {
    const float* x   = (const float*)d_in[0];
    const int*   ei  = (const int*)d_in[1];      // int64 in ref -> int32 from harness
    const float* W0  = (const float*)d_in[2];
    const float* b0  = (const float*)d_in[3];
    const float* g0  = (const float*)d_in[4];
    const float* be0 = (const float*)d_in[5];
    const float* W1  = (const float*)d_in[6];
    const float* b1  = (const float*)d_in[7];
    const float* g1  = (const float*)d_in[8];
    const float* be1 = (const float*)d_in[9];
    const float* W2  = (const float*)d_in[10];
    const float* b2  = (const float*)d_in[11];
    float* out = (float*)d_out;

    const int N  = in_sizes[0] / 128;   // 170000
    const int E  = in_sizes[1] / 2;     // 1200000
    const int NB = (N + 255) >> 8;      // 665 buckets
    const int nb = (N + 255) / 256;
    const int EB = (E + 8191) / 8192;   // 147 edge-chunk blocks

    // ws layout (4B units)
    float* ws     = (float*)d_ws;
    size_t Npad   = ((size_t)N + 511) & ~(size_t)511;
    size_t Epad   = ((size_t)E + 255) & ~(size_t)255;
    float* dinv   = ws;
    int*   rs     = (int*)(ws + Npad);                  // Npad+16
    int*   csr    = rs + Npad + 16;                     // Epad
    unsigned int* ebuf = (unsigned int*)(csr + Epad);   // Epad (packed u32)
    int*   bcnt   = (int*)(ebuf + Epad);                // 1024
    int*   bbase  = bcnt + 1024;                        // 1024
    int*   bcur   = bbase + 1024;                       // 1024
    int*   bsum   = bcur + 1024;                        // 1024
    float* stats0 = (float*)(bsum + 1024);              // 256
    float* stats1 = stats0 + 256;                       // 256
    float* pstats0 = stats1 + 256;                      // 64*256
    float* pstats1 = pstats0 + 64 * 256;                // 64*256
    unsigned short* Wf0 = (unsigned short*)(pstats1 + 64 * 256);
    unsigned short* Wf1 = Wf0 + 16384;
    unsigned short* Wf2 = Wf1 + 16384;
    unsigned short* Hb  = Wf2 + 16384;                  // Npad*128 bf16
    unsigned short* Bb  = Hb + Npad * 128;              // Npad*128 bf16

    hipMemsetAsync(bcnt, 0, 1024 * sizeof(int), stream);
    hipMemsetAsync(pstats0, 0, 2 * 64 * 256 * sizeof(float), stream);

    // ---- CSR build (counting sort) + weight prep ----
    k_bhist    <<<EB, 256, 0, stream>>>(ei, bcnt, E, NB);
    k_bscan    <<<1, 1024, 0, stream>>>(bcnt, bbase, bcur, NB);
    k_bscatter <<<EB, 256, 0, stream>>>(ei, bcur, ebuf, E, NB);
    k_bcount   <<<NB, 256, 0, stream>>>(ebuf, bbase, rs, dinv, N);
    k_scan_part<<<nb, 256, 0, stream>>>(rs, bsum, N);
    k_scan_sums<<<1, 1024, 0, stream>>>(bsum, nb);
    k_scan_add <<<nb, 256, 0, stream>>>(rs, bsum, N);
    k_bplace   <<<NB, 256, 0, stream>>>(ebuf, bbase, rs, csr, N);
    k_prepW    <<<8, 256, 0, stream>>>(W0, Wf0, 128);
    k_prepW    <<<8, 256, 0, stream>>>(W1, Wf1, 128);
    k_prepW    <<<8, 256, 0, stream>>>(W2, Wf2, 40);

    int gemm_grid = (N + 63) / 64;
    int a128_grid = (N + 7) / 8;
    int a40_grid  = (N + 15) / 16;

    // ---- layer 0 ----
    k_gemm_mfma <<<gemm_grid, 256, 0, stream>>>(x, 1, Wf0, Hb, N, nullptr, nullptr, nullptr);
    k_agg128    <<<a128_grid, 256, 0, stream>>>(Hb, rs, csr, dinv, b0, Bb, pstats0, N, E);
    k_statreduce<<<1, 256, 0, stream>>>(pstats0, stats0);

    // ---- layer 1 (BN0+ReLU fused into GEMM staging) ----
    k_gemm_mfma <<<gemm_grid, 256, 0, stream>>>(Bb, 0, Wf1, Hb, N, stats0, g0, be0);
    k_agg128    <<<a128_grid, 256, 0, stream>>>(Hb, rs, csr, dinv, b1, Bb, pstats1, N, E);
    k_statreduce<<<1, 256, 0, stream>>>(pstats1, stats1);

    // ---- layer 2 (BN1+ReLU fused) -> 40 ch ----
    k_gemm_mfma <<<gemm_grid, 256, 0, stream>>>(Bb, 0, Wf2, Hb, N, stats1, g1, be1);
    k_agg40     <<<a40_grid, 256, 0, stream>>>(Hb, rs, csr, dinv, b2, out, N, E);
}

// Round 7
// 660.585 us; speedup vs baseline: 1.3465x; 1.3465x over previous
//
#include <hip/hip_runtime.h>

#define BN_EPS 1e-5f

using bf16x8 = __attribute__((ext_vector_type(8))) short;
using f32x4  = __attribute__((ext_vector_type(4))) float;

__device__ __forceinline__ unsigned int f2bf(float f) {   // RTNE fp32->bf16
    unsigned int u = __float_as_uint(f);
    u += 0x7fffu + ((u >> 16) & 1u);
    return u >> 16;
}
__device__ __forceinline__ float bflo(unsigned int u) { return __uint_as_float(u << 16); }
__device__ __forceinline__ float bfhi(unsigned int u) { return __uint_as_float(u & 0xffff0000u); }

// ================= CSR build: two-phase counting sort by dst ================
// bucket b = dst >> 8 (256 nodes/bucket), NB <= 768. 8192 edges per block.

__global__ __launch_bounds__(256) void k_bhist(const int* __restrict__ ei,
                                               int* __restrict__ bcnt, int E, int NB) {
    __shared__ int h[768];
    for (int i = threadIdx.x; i < 768; i += 256) h[i] = 0;
    __syncthreads();
    int base = blockIdx.x * 8192;
    #pragma unroll
    for (int it = 0; it < 32; ++it) {
        int e = base + it * 256 + threadIdx.x;
        if (e < E) atomicAdd(&h[ei[E + e] >> 8], 1);
    }
    __syncthreads();
    for (int i = threadIdx.x; i < NB; i += 256)
        if (h[i]) atomicAdd(&bcnt[i], h[i]);
}

__global__ __launch_bounds__(1024) void k_bscan(const int* __restrict__ bcnt,
                                                int* __restrict__ bbase,
                                                int* __restrict__ bcur, int NB) {
    __shared__ int s[1024];
    int v = (threadIdx.x < NB) ? bcnt[threadIdx.x] : 0;
    s[threadIdx.x] = v;
    __syncthreads();
    for (int off = 1; off < 1024; off <<= 1) {
        int t = (threadIdx.x >= off) ? s[threadIdx.x - off] : 0;
        __syncthreads();
        s[threadIdx.x] += t;
        __syncthreads();
    }
    if (threadIdx.x < NB) {
        int ex = s[threadIdx.x] - v;
        bbase[threadIdx.x] = ex;
        bcur[threadIdx.x]  = ex;
    }
    if (threadIdx.x == 1023) bbase[NB] = s[1023];
}

__global__ __launch_bounds__(256) void k_bscatter(const int* __restrict__ ei,
                                                  int* __restrict__ bcur,
                                                  unsigned int* __restrict__ ebuf,
                                                  int E, int NB) {
    __shared__ int h[768];
    __shared__ int wb[768];
    for (int i = threadIdx.x; i < 768; i += 256) h[i] = 0;
    __syncthreads();
    int base = blockIdx.x * 8192;
    int rk[32];
    #pragma unroll
    for (int it = 0; it < 32; ++it) {
        int e = base + it * 256 + threadIdx.x;
        rk[it] = (e < E) ? atomicAdd(&h[ei[E + e] >> 8], 1) : 0;
    }
    __syncthreads();
    for (int i = threadIdx.x; i < NB; i += 256) {
        int c = h[i];
        wb[i] = c ? atomicAdd(&bcur[i], c) : 0;
    }
    __syncthreads();
    #pragma unroll
    for (int it = 0; it < 32; ++it) {
        int e = base + it * 256 + threadIdx.x;
        if (e < E) {
            unsigned s = (unsigned)ei[e], d = (unsigned)ei[E + e];
            ebuf[wb[d >> 8] + rk[it]] = s | ((d & 255u) << 24);
        }
    }
}

__global__ __launch_bounds__(256) void k_bcount(const unsigned int* __restrict__ ebuf,
                                                const int* __restrict__ bbase,
                                                int* __restrict__ rs,
                                                float* __restrict__ dinv, int N) {
    __shared__ int cnt[256];
    cnt[threadIdx.x] = 0;
    __syncthreads();
    int b = blockIdx.x;
    int beg = bbase[b], end = bbase[b + 1];
    for (int j = beg + threadIdx.x; j < end; j += 256)
        atomicAdd(&cnt[ebuf[j] >> 24], 1);
    __syncthreads();
    int node = b * 256 + threadIdx.x;
    if (node < N) {
        int c = cnt[threadIdx.x];
        rs[node]   = c;
        dinv[node] = rsqrtf((float)(1 + c));   // +1 self-loop
    }
}

__global__ __launch_bounds__(256) void k_scan_part(int* __restrict__ rs,
                                                   int* __restrict__ bsum, int N) {
    __shared__ int s[256];
    int i = blockIdx.x * 256 + threadIdx.x;
    int v = (i < N) ? rs[i] : 0;
    s[threadIdx.x] = v;
    __syncthreads();
    for (int off = 1; off < 256; off <<= 1) {
        int t = (threadIdx.x >= off) ? s[threadIdx.x - off] : 0;
        __syncthreads();
        s[threadIdx.x] += t;
        __syncthreads();
    }
    if (i < N) rs[i] = s[threadIdx.x] - v;
    if (threadIdx.x == 255) bsum[blockIdx.x] = s[255];
}

__global__ __launch_bounds__(1024) void k_scan_sums(int* __restrict__ bsum, int nb) {
    __shared__ int s[1024];
    int v = (threadIdx.x < nb) ? bsum[threadIdx.x] : 0;
    s[threadIdx.x] = v;
    __syncthreads();
    for (int off = 1; off < 1024; off <<= 1) {
        int t = (threadIdx.x >= off) ? s[threadIdx.x - off] : 0;
        __syncthreads();
        s[threadIdx.x] += t;
        __syncthreads();
    }
    if (threadIdx.x < nb) bsum[threadIdx.x] = s[threadIdx.x] - v;
}

__global__ __launch_bounds__(256) void k_scan_add(int* __restrict__ rs,
                                                  const int* __restrict__ bsum, int N) {
    int i = blockIdx.x * 256 + threadIdx.x;
    if (i < N) rs[i] += bsum[blockIdx.x];
}

__global__ __launch_bounds__(256) void k_bplace(const unsigned int* __restrict__ ebuf,
                                                const int* __restrict__ bbase,
                                                const int* __restrict__ rs,
                                                int* __restrict__ csr, int N) {
    __shared__ int cur[256];
    int b = blockIdx.x;
    int node = b * 256 + threadIdx.x;
    cur[threadIdx.x] = (node < N) ? rs[node] : 0;
    __syncthreads();
    int beg = bbase[b], end = bbase[b + 1];
    for (int j = beg + threadIdx.x; j < end; j += 256) {
        unsigned e = ebuf[j];
        int pos = atomicAdd(&cur[e >> 24], 1);
        csr[pos] = (int)(e & 0x00FFFFFFu);
    }
}

// ==================== weight prep: bf16 B-fragment order ====================
__global__ __launch_bounds__(256) void k_prepW(const float* __restrict__ W,
                                               unsigned short* __restrict__ Wf, int C) {
    int t = blockIdx.x * 256 + threadIdx.x;
    if (t >= 2048) return;
    int lane = t & 63, frag = t >> 6;
    int kt = frag & 3, ct = frag >> 2;
    int r = lane & 15, q = lane >> 4;
    int col = ct * 16 + r;
    int kbase = kt * 32 + q * 8;
    unsigned int v[8];
    #pragma unroll
    for (int j = 0; j < 8; ++j)
        v[j] = (col < C) ? f2bf(W[(size_t)(kbase + j) * C + col]) : 0u;
    uint4 o;
    o.x = v[0] | (v[1] << 16);
    o.y = v[2] | (v[3] << 16);
    o.z = v[4] | (v[5] << 16);
    o.w = v[6] | (v[7] << 16);
    ((uint4*)Wf)[t] = o;
}

// ============================== MFMA GEMM ===================================
__device__ __forceinline__ float bn_apply(float v, int c, const float* stats,
                                          const float* g, const float* be, float invN) {
    float mean = stats[c] * invN;
    float var  = fmaf(-mean, mean, stats[128 + c] * invN);
    float sc   = g[c] * rsqrtf(var + BN_EPS);
    float r    = fmaf(v - mean, sc, be[c]);
    return fmaxf(r, 0.0f);
}

__global__ __launch_bounds__(256) void k_gemm_mfma(
        const void* __restrict__ X, int xf32, const unsigned short* __restrict__ Wf,
        unsigned short* __restrict__ H, int N,
        const float* __restrict__ stats, const float* __restrict__ g,
        const float* __restrict__ be) {
    __shared__ unsigned short aF[16 * 512];   // 16 KB, A frags
    __shared__ unsigned short bF[32 * 512];   // 32 KB, B frags
    const int tid = threadIdx.x;
    const int rowbase = blockIdx.x * 64;
    const float invN = 1.0f / (float)N;

    {   // stage B
        const uint4* src = (const uint4*)Wf;
        uint4* dst = (uint4*)bF;
        #pragma unroll
        for (int i = 0; i < 8; ++i) dst[tid + 256 * i] = src[tid + 256 * i];
    }
    // stage A: one frag-slot per task, BN+ReLU fused
    #pragma unroll
    for (int it = 0; it < 4; ++it) {
        int f = tid + 256 * it;
        int lane = f & 63, frag = f >> 6;
        int kt = frag & 3, rt = frag >> 2;
        int r = lane & 15, q = lane >> 4;
        int row = rowbase + rt * 16 + r;
        int kc = kt * 32 + q * 8;
        float vv[8];
        if (row < N) {
            if (xf32) {
                const float4* xp = (const float4*)((const float*)X + (size_t)row * 128 + kc);
                float4 p0 = xp[0], p1 = xp[1];
                vv[0] = p0.x; vv[1] = p0.y; vv[2] = p0.z; vv[3] = p0.w;
                vv[4] = p1.x; vv[5] = p1.y; vv[6] = p1.z; vv[7] = p1.w;
            } else {
                uint4 p = *((const uint4*)((const unsigned short*)X + (size_t)row * 128 + kc));
                vv[0] = bflo(p.x); vv[1] = bfhi(p.x);
                vv[2] = bflo(p.y); vv[3] = bfhi(p.y);
                vv[4] = bflo(p.z); vv[5] = bfhi(p.z);
                vv[6] = bflo(p.w); vv[7] = bfhi(p.w);
            }
            if (stats) {
                #pragma unroll
                for (int j = 0; j < 8; ++j)
                    vv[j] = bn_apply(vv[j], kc + j, stats, g, be, invN);
            }
        } else {
            #pragma unroll
            for (int j = 0; j < 8; ++j) vv[j] = 0.0f;
        }
        uint4 o;
        o.x = f2bf(vv[0]) | (f2bf(vv[1]) << 16);
        o.y = f2bf(vv[2]) | (f2bf(vv[3]) << 16);
        o.z = f2bf(vv[4]) | (f2bf(vv[5]) << 16);
        o.w = f2bf(vv[6]) | (f2bf(vv[7]) << 16);
        ((uint4*)aF)[f] = o;
    }
    __syncthreads();

    const int wave = tid >> 6, lane = tid & 63;
    f32x4 acc[8];
    #pragma unroll
    for (int ct = 0; ct < 8; ++ct) acc[ct] = (f32x4){0.f, 0.f, 0.f, 0.f};

    #pragma unroll
    for (int kt = 0; kt < 4; ++kt) {
        bf16x8 a = ((const bf16x8*)aF)[(wave * 4 + kt) * 64 + lane];
        #pragma unroll
        for (int ct = 0; ct < 8; ++ct) {
            bf16x8 b = ((const bf16x8*)bF)[(ct * 4 + kt) * 64 + lane];
            acc[ct] = __builtin_amdgcn_mfma_f32_16x16x32_bf16(a, b, acc[ct], 0, 0, 0);
        }
    }

    const int q = lane >> 4, r = lane & 15;   // C/D: col=lane&15, row=q*4+reg
    #pragma unroll
    for (int ct = 0; ct < 8; ++ct) {
        #pragma unroll
        for (int i = 0; i < 4; ++i) {
            int row = rowbase + wave * 16 + q * 4 + i;
            if (row < N)
                H[(size_t)row * 128 + ct * 16 + r] = (unsigned short)f2bf(acc[ct][i]);
        }
    }
}

// ========================= gather-based aggregate ===========================
// out_bf16[d] = b + H[d]*dinv[d]^2 + sum_s H[s]*dinv[s]*dinv[d]
// No block barrier, no LDS — waves retire independently (R6 lesson).
__global__ __launch_bounds__(256) void k_agg128(
        const unsigned short* __restrict__ H, const int* __restrict__ rs,
        const int* __restrict__ csr_src, const float* __restrict__ dinv,
        const float* __restrict__ b, unsigned short* __restrict__ outb, int N, int E) {
    int lane = threadIdx.x & 31;
    int node = blockIdx.x * 8 + (threadIdx.x >> 5);
    if (node >= N) return;
    float dd  = dinv[node];
    int   beg = rs[node];
    int   end = (node == N - 1) ? E : rs[node + 1];
    uint2 hp  = ((const uint2*)(H + (size_t)node * 128))[lane];
    float4 bb = ((const float4*)b)[lane];
    float  sl = dd * dd;
    float4 acc = make_float4(fmaf(bflo(hp.x), sl, bb.x), fmaf(bfhi(hp.x), sl, bb.y),
                             fmaf(bflo(hp.y), sl, bb.z), fmaf(bfhi(hp.y), sl, bb.w));
    int j = beg;
    for (; j + 4 <= end; j += 4) {           // 4 row-gathers in flight
        int s0 = csr_src[j], s1 = csr_src[j + 1];
        int s2 = csr_src[j + 2], s3 = csr_src[j + 3];
        float n0 = dinv[s0] * dd, n1 = dinv[s1] * dd;
        float n2 = dinv[s2] * dd, n3 = dinv[s3] * dd;
        uint2 v0 = ((const uint2*)(H + (size_t)s0 * 128))[lane];
        uint2 v1 = ((const uint2*)(H + (size_t)s1 * 128))[lane];
        uint2 v2 = ((const uint2*)(H + (size_t)s2 * 128))[lane];
        uint2 v3 = ((const uint2*)(H + (size_t)s3 * 128))[lane];
        acc.x = fmaf(bflo(v0.x), n0, fmaf(bflo(v1.x), n1,
                fmaf(bflo(v2.x), n2, fmaf(bflo(v3.x), n3, acc.x))));
        acc.y = fmaf(bfhi(v0.x), n0, fmaf(bfhi(v1.x), n1,
                fmaf(bfhi(v2.x), n2, fmaf(bfhi(v3.x), n3, acc.y))));
        acc.z = fmaf(bflo(v0.y), n0, fmaf(bflo(v1.y), n1,
                fmaf(bflo(v2.y), n2, fmaf(bflo(v3.y), n3, acc.z))));
        acc.w = fmaf(bfhi(v0.y), n0, fmaf(bfhi(v1.y), n1,
                fmaf(bfhi(v2.y), n2, fmaf(bfhi(v3.y), n3, acc.w))));
    }
    for (; j < end; ++j) {
        int s0 = csr_src[j];
        float n0 = dinv[s0] * dd;
        uint2 v0 = ((const uint2*)(H + (size_t)s0 * 128))[lane];
        acc.x = fmaf(bflo(v0.x), n0, acc.x);
        acc.y = fmaf(bfhi(v0.x), n0, acc.y);
        acc.z = fmaf(bflo(v0.y), n0, acc.z);
        acc.w = fmaf(bfhi(v0.y), n0, acc.w);
    }
    uint2 o;
    o.x = f2bf(acc.x) | (f2bf(acc.y) << 16);
    o.y = f2bf(acc.z) | (f2bf(acc.w) << 16);
    ((uint2*)(outb + (size_t)node * 128))[lane] = o;
}

// 40-ch final: f32 output
__global__ __launch_bounds__(256) void k_agg40(
        const unsigned short* __restrict__ H, const int* __restrict__ rs,
        const int* __restrict__ csr_src, const float* __restrict__ dinv,
        const float* __restrict__ b, float* __restrict__ out, int N, int E) {
    int lane = threadIdx.x & 15;
    int node = blockIdx.x * 16 + (threadIdx.x >> 4);
    if (node >= N || lane >= 10) return;
    float dd  = dinv[node];
    int   beg = rs[node];
    int   end = (node == N - 1) ? E : rs[node + 1];
    uint2 hp  = ((const uint2*)(H + (size_t)node * 128))[lane];
    float4 bb = ((const float4*)b)[lane];
    float  sl = dd * dd;
    float4 acc = make_float4(fmaf(bflo(hp.x), sl, bb.x), fmaf(bfhi(hp.x), sl, bb.y),
                             fmaf(bflo(hp.y), sl, bb.z), fmaf(bfhi(hp.y), sl, bb.w));
    int j = beg;
    for (; j + 2 <= end; j += 2) {
        int s0 = csr_src[j], s1 = csr_src[j + 1];
        float n0 = dinv[s0] * dd, n1 = dinv[s1] * dd;
        uint2 v0 = ((const uint2*)(H + (size_t)s0 * 128))[lane];
        uint2 v1 = ((const uint2*)(H + (size_t)s1 * 128))[lane];
        acc.x = fmaf(bflo(v0.x), n0, fmaf(bflo(v1.x), n1, acc.x));
        acc.y = fmaf(bfhi(v0.x), n0, fmaf(bfhi(v1.x), n1, acc.y));
        acc.z = fmaf(bflo(v0.y), n0, fmaf(bflo(v1.y), n1, acc.z));
        acc.w = fmaf(bfhi(v0.y), n0, fmaf(bfhi(v1.y), n1, acc.w));
    }
    if (j < end) {
        int s0 = csr_src[j];
        float n0 = dinv[s0] * dd;
        uint2 v0 = ((const uint2*)(H + (size_t)s0 * 128))[lane];
        acc.x = fmaf(bflo(v0.x), n0, acc.x);
        acc.y = fmaf(bfhi(v0.x), n0, acc.y);
        acc.z = fmaf(bflo(v0.y), n0, acc.z);
        acc.w = fmaf(bfhi(v0.y), n0, acc.w);
    }
    ((float4*)(out + (size_t)node * 40))[lane] = acc;
}

// =============================== BN stats ===================================
__global__ __launch_bounds__(128) void k_bnstats(
        const unsigned short* __restrict__ Hb, float* __restrict__ stats, int N) {
    int c = threadIdx.x;
    float s = 0.f, s2 = 0.f;
    for (int r = blockIdx.x; r < N; r += gridDim.x) {
        float v = bflo((unsigned)Hb[(size_t)r * 128 + c]);
        s += v;
        s2 = fmaf(v, v, s2);
    }
    unsafeAtomicAdd(&stats[c], s);
    unsafeAtomicAdd(&stats[128 + c], s2);
}

// ================================ launch ====================================
extern "C" void kernel_launch(void* const* d_in, const int* in_sizes, int n_in,
                              void* d_out, int out_size, void* d_ws, size_t ws_size,
                              hipStream_t stream) {
    const float* x   = (const float*)d_in[0];
    const int*   ei  = (const int*)d_in[1];      // int64 in ref -> int32 from harness
    const float* W0  = (const float*)d_in[2];
    const float* b0  = (const float*)d_in[3];
    const float* g0  = (const float*)d_in[4];
    const float* be0 = (const float*)d_in[5];
    const float* W1  = (const float*)d_in[6];
    const float* b1  = (const float*)d_in[7];
    const float* g1  = (const float*)d_in[8];
    const float* be1 = (const float*)d_in[9];
    const float* W2  = (const float*)d_in[10];
    const float* b2  = (const float*)d_in[11];
    float* out = (float*)d_out;

    const int N  = in_sizes[0] / 128;   // 170000
    const int E  = in_sizes[1] / 2;     // 1200000
    const int NB = (N + 255) >> 8;      // 665 buckets
    const int nb = (N + 255) / 256;
    const int EB = (E + 8191) / 8192;   // 147 edge-chunk blocks

    // ws layout (4B units)
    float* ws     = (float*)d_ws;
    size_t Npad   = ((size_t)N + 511) & ~(size_t)511;
    size_t Epad   = ((size_t)E + 255) & ~(size_t)255;
    float* dinv   = ws;
    int*   rs     = (int*)(ws + Npad);                  // Npad+16
    int*   csr    = rs + Npad + 16;                     // Epad
    unsigned int* ebuf = (unsigned int*)(csr + Epad);   // Epad (packed u32)
    int*   bcnt   = (int*)(ebuf + Epad);                // 1024
    int*   bbase  = bcnt + 1024;                        // 1024
    int*   bcur   = bbase + 1024;                       // 1024
    int*   bsum   = bcur + 1024;                        // 1024
    float* stats0 = (float*)(bsum + 1024);              // 256
    float* stats1 = stats0 + 256;                       // 256
    unsigned short* Wf0 = (unsigned short*)(stats1 + 256);
    unsigned short* Wf1 = Wf0 + 16384;
    unsigned short* Wf2 = Wf1 + 16384;
    unsigned short* Hb  = Wf2 + 16384;                  // Npad*128 bf16
    unsigned short* Bb  = Hb + Npad * 128;              // Npad*128 bf16

    hipMemsetAsync(bcnt, 0, 1024 * sizeof(int), stream);
    hipMemsetAsync(stats0, 0, 512 * sizeof(float), stream);

    // ---- CSR build (counting sort) + weight prep ----
    k_bhist    <<<EB, 256, 0, stream>>>(ei, bcnt, E, NB);
    k_bscan    <<<1, 1024, 0, stream>>>(bcnt, bbase, bcur, NB);
    k_bscatter <<<EB, 256, 0, stream>>>(ei, bcur, ebuf, E, NB);
    k_bcount   <<<NB, 256, 0, stream>>>(ebuf, bbase, rs, dinv, N);
    k_scan_part<<<nb, 256, 0, stream>>>(rs, bsum, N);
    k_scan_sums<<<1, 1024, 0, stream>>>(bsum, nb);
    k_scan_add <<<nb, 256, 0, stream>>>(rs, bsum, N);
    k_bplace   <<<NB, 256, 0, stream>>>(ebuf, bbase, rs, csr, N);
    k_prepW    <<<8, 256, 0, stream>>>(W0, Wf0, 128);
    k_prepW    <<<8, 256, 0, stream>>>(W1, Wf1, 128);
    k_prepW    <<<8, 256, 0, stream>>>(W2, Wf2, 40);

    int gemm_grid = (N + 63) / 64;
    int a128_grid = (N + 7) / 8;
    int a40_grid  = (N + 15) / 16;

    // ---- layer 0 ----
    k_gemm_mfma<<<gemm_grid, 256, 0, stream>>>(x, 1, Wf0, Hb, N, nullptr, nullptr, nullptr);
    k_agg128   <<<a128_grid, 256, 0, stream>>>(Hb, rs, csr, dinv, b0, Bb, N, E);
    k_bnstats  <<<1024, 128, 0, stream>>>(Bb, stats0, N);

    // ---- layer 1 (BN0+ReLU fused into GEMM staging) ----
    k_gemm_mfma<<<gemm_grid, 256, 0, stream>>>(Bb, 0, Wf1, Hb, N, stats0, g0, be0);
    k_agg128   <<<a128_grid, 256, 0, stream>>>(Hb, rs, csr, dinv, b1, Bb, N, E);
    k_bnstats  <<<1024, 128, 0, stream>>>(Bb, stats1, N);

    // ---- layer 2 (BN1+ReLU fused) -> 40 ch ----
    k_gemm_mfma<<<gemm_grid, 256, 0, stream>>>(Bb, 0, Wf2, Hb, N, stats1, g1, be1);
    k_agg40    <<<a40_grid, 256, 0, stream>>>(Hb, rs, csr, dinv, b2, out, N, E);
}

// Round 8
// 565.540 us; speedup vs baseline: 1.5728x; 1.1681x over previous
//
#include <hip/hip_runtime.h>

#define BN_EPS 1e-5f
#define CAP 3072   // per-bucket edge capacity (mean 1805, +30 sigma; guarded)

using bf16x8 = __attribute__((ext_vector_type(8))) short;
using f32x4  = __attribute__((ext_vector_type(4))) float;

__device__ __forceinline__ unsigned int f2bf(float f) {   // RTNE fp32->bf16
    unsigned int u = __float_as_uint(f);
    u += 0x7fffu + ((u >> 16) & 1u);
    return u >> 16;
}
__device__ __forceinline__ float bflo(unsigned int u) { return __uint_as_float(u << 16); }
__device__ __forceinline__ float bfhi(unsigned int u) { return __uint_as_float(u & 0xffff0000u); }

// ================================ init ======================================
// bucket cursors + BN stats zero (replaces 2 memsets + scan-prep)
__global__ __launch_bounds__(1024) void k_init(int* __restrict__ bcur,
                                               float* __restrict__ stats, int NB) {
    int t = threadIdx.x;
    if (t < NB) bcur[t] = t * CAP;
    if (t < 512) stats[t] = 0.f;
}

// ===================== scatter edges into fixed buckets =====================
// bucket b = dst>>8.  8192 edges/block, per-block LDS hist + one chunk claim
// per (block,bucket), packed u32 (src | dst_lo<<24).
__global__ __launch_bounds__(256) void k_bscatter(const int* __restrict__ ei,
                                                  int* __restrict__ bcur,
                                                  unsigned int* __restrict__ ebuf,
                                                  int E, int NB) {
    __shared__ int h[768];
    __shared__ int wb[768];
    for (int i = threadIdx.x; i < 768; i += 256) h[i] = 0;
    __syncthreads();
    int base = blockIdx.x * 8192;
    int rk[32];
    #pragma unroll
    for (int it = 0; it < 32; ++it) {
        int e = base + it * 256 + threadIdx.x;
        rk[it] = (e < E) ? atomicAdd(&h[ei[E + e] >> 8], 1) : 0;
    }
    __syncthreads();
    for (int i = threadIdx.x; i < NB; i += 256) {
        int c = h[i];
        wb[i] = c ? atomicAdd(&bcur[i], c) : 0;
    }
    __syncthreads();
    #pragma unroll
    for (int it = 0; it < 32; ++it) {
        int e = base + it * 256 + threadIdx.x;
        if (e < E) {
            unsigned s = (unsigned)ei[e], d = (unsigned)ei[E + e];
            int bk = (int)(d >> 8);
            int pos = wb[bk] + rk[it];
            if (pos < (bk + 1) * CAP)              // overflow guard (never hit)
                ebuf[pos] = s | ((d & 255u) << 24);
        }
    }
}

// ================== per-bucket finalize: count+scan+place ===================
// Block b owns bucket b: node counts -> rs/re/dinv (coalesced), then place
// srcs into csr[b*CAP ...] via LDS cursors.  No global scan needed.
__global__ __launch_bounds__(256) void k_bfinal(const unsigned int* __restrict__ ebuf,
                                                const int* __restrict__ bcur,
                                                int* __restrict__ csr,
                                                int* __restrict__ rs,
                                                int* __restrict__ re,
                                                float* __restrict__ dinv, int N) {
    __shared__ int cnt[256];
    __shared__ int scn[256];
    __shared__ int cur[256];
    const int t = threadIdx.x, b = blockIdx.x;
    const int beg = b * CAP;
    const int cntE = min(bcur[b] - beg, CAP);
    cnt[t] = 0;
    __syncthreads();
    for (int j = t; j < cntE; j += 256)
        atomicAdd(&cnt[ebuf[beg + j] >> 24], 1);
    __syncthreads();
    int v = cnt[t];
    scn[t] = v;
    __syncthreads();
    for (int off = 1; off < 256; off <<= 1) {
        int x = (t >= off) ? scn[t - off] : 0;
        __syncthreads();
        scn[t] += x;
        __syncthreads();
    }
    int excl = scn[t] - v;
    int node = b * 256 + t;
    if (node < N) {
        rs[node]   = beg + excl;
        re[node]   = beg + excl + v;
        dinv[node] = rsqrtf((float)(1 + v));   // +1 self-loop
    }
    cur[t] = beg + excl;
    __syncthreads();
    for (int j = t; j < cntE; j += 256) {
        unsigned e = ebuf[beg + j];
        int pos = atomicAdd(&cur[e >> 24], 1);
        csr[pos] = (int)(e & 0x00FFFFFFu);
    }
}

// ============== weight prep: all 3 weights, bf16 B-frag order ===============
__global__ __launch_bounds__(256) void k_prepW3(const float* __restrict__ W0,
                                                const float* __restrict__ W1,
                                                const float* __restrict__ W2,
                                                unsigned short* __restrict__ Wf) {
    int t = blockIdx.x * 256 + threadIdx.x;   // 0..6143
    int wid = t >> 11;                        // 0,1,2
    int f = t & 2047;
    const float* W = (wid == 0) ? W0 : (wid == 1) ? W1 : W2;
    int C = (wid == 2) ? 40 : 128;
    int lane = f & 63, frag = f >> 6;
    int kt = frag & 3, ct = frag >> 2;
    int r = lane & 15, q = lane >> 4;
    int col = ct * 16 + r;
    int kbase = kt * 32 + q * 8;
    unsigned int v[8];
    #pragma unroll
    for (int j = 0; j < 8; ++j)
        v[j] = (col < C) ? f2bf(W[(size_t)(kbase + j) * C + col]) : 0u;
    uint4 o;
    o.x = v[0] | (v[1] << 16);
    o.y = v[2] | (v[3] << 16);
    o.z = v[4] | (v[5] << 16);
    o.w = v[6] | (v[7] << 16);
    ((uint4*)Wf)[t] = o;
}

// ============================== MFMA GEMM ===================================
__device__ __forceinline__ float bn_apply(float v, int c, const float* stats,
                                          const float* g, const float* be, float invN) {
    float mean = stats[c] * invN;
    float var  = fmaf(-mean, mean, stats[128 + c] * invN);
    float sc   = g[c] * rsqrtf(var + BN_EPS);
    float r    = fmaf(v - mean, sc, be[c]);
    return fmaxf(r, 0.0f);
}

// H[N,OST]_bf16 = bf16( bn_relu(X)[N,128] @ W[:, :NOCT*16] )
template <int NOCT, int OST>
__global__ __launch_bounds__(256) void k_gemm_mfma(
        const void* __restrict__ X, int xf32, const unsigned short* __restrict__ Wf,
        unsigned short* __restrict__ H, int N,
        const float* __restrict__ stats, const float* __restrict__ g,
        const float* __restrict__ be) {
    __shared__ unsigned short aF[16 * 512];
    __shared__ unsigned short bF[NOCT * 4 * 512];
    const int tid = threadIdx.x;
    const int rowbase = blockIdx.x * 64;
    const float invN = 1.0f / (float)N;

    {   // stage B: NOCT col-tiles, lane-contiguous copy
        const uint4* src = (const uint4*)Wf;
        uint4* dst = (uint4*)bF;
        #pragma unroll
        for (int i = 0; i < NOCT; ++i) dst[tid + 256 * i] = src[tid + 256 * i];
    }
    // stage A: one frag-slot per task, BN+ReLU fused
    #pragma unroll
    for (int it = 0; it < 4; ++it) {
        int f = tid + 256 * it;
        int lane = f & 63, frag = f >> 6;
        int kt = frag & 3, rt = frag >> 2;
        int r = lane & 15, q = lane >> 4;
        int row = rowbase + rt * 16 + r;
        int kc = kt * 32 + q * 8;
        float vv[8];
        if (row < N) {
            if (xf32) {
                const float4* xp = (const float4*)((const float*)X + (size_t)row * 128 + kc);
                float4 p0 = xp[0], p1 = xp[1];
                vv[0] = p0.x; vv[1] = p0.y; vv[2] = p0.z; vv[3] = p0.w;
                vv[4] = p1.x; vv[5] = p1.y; vv[6] = p1.z; vv[7] = p1.w;
            } else {
                uint4 p = *((const uint4*)((const unsigned short*)X + (size_t)row * 128 + kc));
                vv[0] = bflo(p.x); vv[1] = bfhi(p.x);
                vv[2] = bflo(p.y); vv[3] = bfhi(p.y);
                vv[4] = bflo(p.z); vv[5] = bfhi(p.z);
                vv[6] = bflo(p.w); vv[7] = bfhi(p.w);
            }
            if (stats) {
                #pragma unroll
                for (int j = 0; j < 8; ++j)
                    vv[j] = bn_apply(vv[j], kc + j, stats, g, be, invN);
            }
        } else {
            #pragma unroll
            for (int j = 0; j < 8; ++j) vv[j] = 0.0f;
        }
        uint4 o;
        o.x = f2bf(vv[0]) | (f2bf(vv[1]) << 16);
        o.y = f2bf(vv[2]) | (f2bf(vv[3]) << 16);
        o.z = f2bf(vv[4]) | (f2bf(vv[5]) << 16);
        o.w = f2bf(vv[6]) | (f2bf(vv[7]) << 16);
        ((uint4*)aF)[f] = o;
    }
    __syncthreads();

    const int wave = tid >> 6, lane = tid & 63;
    f32x4 acc[NOCT];
    #pragma unroll
    for (int ct = 0; ct < NOCT; ++ct) acc[ct] = (f32x4){0.f, 0.f, 0.f, 0.f};

    #pragma unroll
    for (int kt = 0; kt < 4; ++kt) {
        bf16x8 a = ((const bf16x8*)aF)[(wave * 4 + kt) * 64 + lane];
        #pragma unroll
        for (int ct = 0; ct < NOCT; ++ct) {
            bf16x8 b = ((const bf16x8*)bF)[(ct * 4 + kt) * 64 + lane];
            acc[ct] = __builtin_amdgcn_mfma_f32_16x16x32_bf16(a, b, acc[ct], 0, 0, 0);
        }
    }

    const int q = lane >> 4, r = lane & 15;   // C/D: col=lane&15, row=q*4+reg
    #pragma unroll
    for (int ct = 0; ct < NOCT; ++ct) {
        #pragma unroll
        for (int i = 0; i < 4; ++i) {
            int row = rowbase + wave * 16 + q * 4 + i;
            if (row < N)
                H[(size_t)row * OST + ct * 16 + r] = (unsigned short)f2bf(acc[ct][i]);
        }
    }
}

// ========================= gather-based aggregate ===========================
// 16 lanes/node, uint4 (8ch) per lane: half the load instrs of 32-lane uint2.
__global__ __launch_bounds__(256) void k_agg128(
        const unsigned short* __restrict__ H, const int* __restrict__ rs,
        const int* __restrict__ re, const int* __restrict__ csr,
        const float* __restrict__ dinv, const float* __restrict__ b,
        unsigned short* __restrict__ outb, int N) {
    int lane = threadIdx.x & 15;
    int node = blockIdx.x * 16 + (threadIdx.x >> 4);
    if (node >= N) return;
    float dd  = dinv[node];
    int   beg = rs[node];
    int   end = re[node];
    uint4 hp  = ((const uint4*)(H + (size_t)node * 128))[lane];
    float4 bb0 = ((const float4*)b)[lane * 2];
    float4 bb1 = ((const float4*)b)[lane * 2 + 1];
    float sl = dd * dd;
    float a0 = fmaf(bflo(hp.x), sl, bb0.x), a1 = fmaf(bfhi(hp.x), sl, bb0.y);
    float a2 = fmaf(bflo(hp.y), sl, bb0.z), a3 = fmaf(bfhi(hp.y), sl, bb0.w);
    float a4 = fmaf(bflo(hp.z), sl, bb1.x), a5 = fmaf(bfhi(hp.z), sl, bb1.y);
    float a6 = fmaf(bflo(hp.w), sl, bb1.z), a7 = fmaf(bfhi(hp.w), sl, bb1.w);
    int j = beg;
    for (; j + 2 <= end; j += 2) {
        int s0 = csr[j], s1 = csr[j + 1];
        float n0 = dinv[s0] * dd, n1 = dinv[s1] * dd;
        uint4 v0 = ((const uint4*)(H + (size_t)s0 * 128))[lane];
        uint4 v1 = ((const uint4*)(H + (size_t)s1 * 128))[lane];
        a0 = fmaf(bflo(v0.x), n0, fmaf(bflo(v1.x), n1, a0));
        a1 = fmaf(bfhi(v0.x), n0, fmaf(bfhi(v1.x), n1, a1));
        a2 = fmaf(bflo(v0.y), n0, fmaf(bflo(v1.y), n1, a2));
        a3 = fmaf(bfhi(v0.y), n0, fmaf(bfhi(v1.y), n1, a3));
        a4 = fmaf(bflo(v0.z), n0, fmaf(bflo(v1.z), n1, a4));
        a5 = fmaf(bfhi(v0.z), n0, fmaf(bfhi(v1.z), n1, a5));
        a6 = fmaf(bflo(v0.w), n0, fmaf(bflo(v1.w), n1, a6));
        a7 = fmaf(bfhi(v0.w), n0, fmaf(bfhi(v1.w), n1, a7));
    }
    if (j < end) {
        int s0 = csr[j];
        float n0 = dinv[s0] * dd;
        uint4 v0 = ((const uint4*)(H + (size_t)s0 * 128))[lane];
        a0 = fmaf(bflo(v0.x), n0, a0); a1 = fmaf(bfhi(v0.x), n0, a1);
        a2 = fmaf(bflo(v0.y), n0, a2); a3 = fmaf(bfhi(v0.y), n0, a3);
        a4 = fmaf(bflo(v0.z), n0, a4); a5 = fmaf(bfhi(v0.z), n0, a5);
        a6 = fmaf(bflo(v0.w), n0, a6); a7 = fmaf(bfhi(v0.w), n0, a7);
    }
    uint4 o;
    o.x = f2bf(a0) | (f2bf(a1) << 16);
    o.y = f2bf(a2) | (f2bf(a3) << 16);
    o.z = f2bf(a4) | (f2bf(a5) << 16);
    o.w = f2bf(a6) | (f2bf(a7) << 16);
    ((uint4*)(outb + (size_t)node * 128))[lane] = o;
}

// 40-ch final from compact stride-48 H: smaller working set for the gather
__global__ __launch_bounds__(256) void k_agg40(
        const unsigned short* __restrict__ H, const int* __restrict__ rs,
        const int* __restrict__ re, const int* __restrict__ csr,
        const float* __restrict__ dinv, const float* __restrict__ b,
        float* __restrict__ out, int N) {
    int lane = threadIdx.x & 15;
    int node = blockIdx.x * 16 + (threadIdx.x >> 4);
    if (node >= N || lane >= 10) return;
    float dd  = dinv[node];
    int   beg = rs[node];
    int   end = re[node];
    uint2 hp  = ((const uint2*)(H + (size_t)node * 48))[lane];
    float4 bb = ((const float4*)b)[lane];
    float  sl = dd * dd;
    float4 acc = make_float4(fmaf(bflo(hp.x), sl, bb.x), fmaf(bfhi(hp.x), sl, bb.y),
                             fmaf(bflo(hp.y), sl, bb.z), fmaf(bfhi(hp.y), sl, bb.w));
    int j = beg;
    for (; j + 2 <= end; j += 2) {
        int s0 = csr[j], s1 = csr[j + 1];
        float n0 = dinv[s0] * dd, n1 = dinv[s1] * dd;
        uint2 v0 = ((const uint2*)(H + (size_t)s0 * 48))[lane];
        uint2 v1 = ((const uint2*)(H + (size_t)s1 * 48))[lane];
        acc.x = fmaf(bflo(v0.x), n0, fmaf(bflo(v1.x), n1, acc.x));
        acc.y = fmaf(bfhi(v0.x), n0, fmaf(bfhi(v1.x), n1, acc.y));
        acc.z = fmaf(bflo(v0.y), n0, fmaf(bflo(v1.y), n1, acc.z));
        acc.w = fmaf(bfhi(v0.y), n0, fmaf(bfhi(v1.y), n1, acc.w));
    }
    if (j < end) {
        int s0 = csr[j];
        float n0 = dinv[s0] * dd;
        uint2 v0 = ((const uint2*)(H + (size_t)s0 * 48))[lane];
        acc.x = fmaf(bflo(v0.x), n0, acc.x);
        acc.y = fmaf(bfhi(v0.x), n0, acc.y);
        acc.z = fmaf(bflo(v0.y), n0, acc.z);
        acc.w = fmaf(bfhi(v0.y), n0, acc.w);
    }
    ((float4*)(out + (size_t)node * 40))[lane] = acc;
}

// =============================== BN stats ===================================
__global__ __launch_bounds__(128) void k_bnstats(
        const unsigned short* __restrict__ Hb, float* __restrict__ stats, int N) {
    int c = threadIdx.x;
    float s = 0.f, s2 = 0.f;
    for (int r = blockIdx.x; r < N; r += gridDim.x) {
        float v = bflo((unsigned)Hb[(size_t)r * 128 + c]);
        s += v;
        s2 = fmaf(v, v, s2);
    }
    unsafeAtomicAdd(&stats[c], s);
    unsafeAtomicAdd(&stats[128 + c], s2);
}

// ================================ launch ====================================
extern "C" void kernel_launch(void* const* d_in, const int* in_sizes, int n_in,
                              void* d_out, int out_size, void* d_ws, size_t ws_size,
                              hipStream_t stream) {
    const float* x   = (const float*)d_in[0];
    const int*   ei  = (const int*)d_in[1];      // int64 in ref -> int32 from harness
    const float* W0  = (const float*)d_in[2];
    const float* b0  = (const float*)d_in[3];
    const float* g0  = (const float*)d_in[4];
    const float* be0 = (const float*)d_in[5];
    const float* W1  = (const float*)d_in[6];
    const float* b1  = (const float*)d_in[7];
    const float* g1  = (const float*)d_in[8];
    const float* be1 = (const float*)d_in[9];
    const float* W2  = (const float*)d_in[10];
    const float* b2  = (const float*)d_in[11];
    float* out = (float*)d_out;

    const int N  = in_sizes[0] / 128;   // 170000
    const int E  = in_sizes[1] / 2;     // 1200000
    const int NB = (N + 255) >> 8;      // 665 buckets
    const int EB = (E + 8191) / 8192;   // 147 edge-chunk blocks

    // ws layout (4B units)
    float* ws   = (float*)d_ws;
    size_t Npad = ((size_t)N + 511) & ~(size_t)511;
    size_t BCAP = (size_t)NB * CAP;                     // 2,042,880
    float* dinv = ws;
    int*   rs   = (int*)(ws + Npad);
    int*   re   = rs + Npad;
    int*   csr  = re + Npad;                            // BCAP
    unsigned int* ebuf = (unsigned int*)(csr + BCAP);   // BCAP
    int*   bcur = (int*)(ebuf + BCAP);                  // 1024
    float* stats0 = (float*)(bcur + 1024);              // 256
    float* stats1 = stats0 + 256;                       // 256
    unsigned short* Wf = (unsigned short*)(stats1 + 256); // 3*16384 ushort
    unsigned short* Hb = Wf + 3 * 16384;                // Npad*128 bf16
    unsigned short* Bb = Hb + Npad * 128;               // Npad*128 bf16

    // ---- CSR build (4 dispatches, no memsets) ----
    k_init    <<<1, 1024, 0, stream>>>(bcur, stats0, NB);
    k_bscatter<<<EB, 256, 0, stream>>>(ei, bcur, ebuf, E, NB);
    k_bfinal  <<<NB, 256, 0, stream>>>(ebuf, bcur, csr, rs, re, dinv, N);
    k_prepW3  <<<24, 256, 0, stream>>>(W0, W1, W2, Wf);

    int gemm_grid = (N + 63) / 64;
    int agg_grid  = (N + 15) / 16;

    // ---- layer 0 ----
    k_gemm_mfma<8, 128><<<gemm_grid, 256, 0, stream>>>(x, 1, Wf, Hb, N,
                                                       nullptr, nullptr, nullptr);
    k_agg128<<<agg_grid, 256, 0, stream>>>(Hb, rs, re, csr, dinv, b0, Bb, N);
    k_bnstats<<<1024, 128, 0, stream>>>(Bb, stats0, N);

    // ---- layer 1 (BN0+ReLU fused into GEMM staging) ----
    k_gemm_mfma<8, 128><<<gemm_grid, 256, 0, stream>>>(Bb, 0, Wf + 16384, Hb, N,
                                                       stats0, g0, be0);
    k_agg128<<<agg_grid, 256, 0, stream>>>(Hb, rs, re, csr, dinv, b1, Bb, N);
    k_bnstats<<<1024, 128, 0, stream>>>(Bb, stats1, N);

    // ---- layer 2 (BN1+ReLU fused) -> compact 48-stride H -> 40-ch out ----
    k_gemm_mfma<3, 48><<<gemm_grid, 256, 0, stream>>>(Bb, 0, Wf + 2 * 16384, Hb, N,
                                                      stats1, g1, be1);
    k_agg40<<<agg_grid, 256, 0, stream>>>(Hb, rs, re, csr, dinv, b2, out, N);
}

// Round 9
// 475.341 us; speedup vs baseline: 1.8713x; 1.1898x over previous
//
#include <hip/hip_runtime.h>

#define BN_EPS 1e-5f
#define CAP 3072   // per-bucket edge capacity (mean 1805, +30 sigma; guarded)

using bf16x8 = __attribute__((ext_vector_type(8))) short;
using f32x4  = __attribute__((ext_vector_type(4))) float;

__device__ __forceinline__ unsigned int f2bf(float f) {   // RTNE fp32->bf16
    unsigned int u = __float_as_uint(f);
    u += 0x7fffu + ((u >> 16) & 1u);
    return u >> 16;
}
__device__ __forceinline__ float bflo(unsigned int u) { return __uint_as_float(u << 16); }
__device__ __forceinline__ float bfhi(unsigned int u) { return __uint_as_float(u & 0xffff0000u); }

// ================================ init ======================================
__global__ __launch_bounds__(1024) void k_init(int* __restrict__ bcur,
                                               float* __restrict__ stats, int NB) {
    int t = threadIdx.x;
    if (t < NB) bcur[t] = t * CAP;
    if (t < 512) stats[t] = 0.f;
}

// ===================== scatter edges into fixed buckets =====================
__global__ __launch_bounds__(256) void k_bscatter(const int* __restrict__ ei,
                                                  int* __restrict__ bcur,
                                                  unsigned int* __restrict__ ebuf,
                                                  int E, int NB) {
    __shared__ int h[768];
    __shared__ int wb[768];
    for (int i = threadIdx.x; i < 768; i += 256) h[i] = 0;
    __syncthreads();
    int base = blockIdx.x * 8192;
    int rk[32];
    #pragma unroll
    for (int it = 0; it < 32; ++it) {
        int e = base + it * 256 + threadIdx.x;
        rk[it] = (e < E) ? atomicAdd(&h[ei[E + e] >> 8], 1) : 0;
    }
    __syncthreads();
    for (int i = threadIdx.x; i < NB; i += 256) {
        int c = h[i];
        wb[i] = c ? atomicAdd(&bcur[i], c) : 0;
    }
    __syncthreads();
    #pragma unroll
    for (int it = 0; it < 32; ++it) {
        int e = base + it * 256 + threadIdx.x;
        if (e < E) {
            unsigned s = (unsigned)ei[e], d = (unsigned)ei[E + e];
            int bk = (int)(d >> 8);
            int pos = wb[bk] + rk[it];
            if (pos < (bk + 1) * CAP)              // overflow guard (never hit)
                ebuf[pos] = s | ((d & 255u) << 24);
        }
    }
}

// ================== per-bucket finalize: count+scan+place ===================
__global__ __launch_bounds__(256) void k_bfinal(const unsigned int* __restrict__ ebuf,
                                                const int* __restrict__ bcur,
                                                int* __restrict__ csr,
                                                int* __restrict__ rs,
                                                int* __restrict__ re,
                                                float* __restrict__ dinv, int N) {
    __shared__ int cnt[256];
    __shared__ int scn[256];
    __shared__ int cur[256];
    const int t = threadIdx.x, b = blockIdx.x;
    const int beg = b * CAP;
    const int cntE = min(bcur[b] - beg, CAP);
    cnt[t] = 0;
    __syncthreads();
    for (int j = t; j < cntE; j += 256)
        atomicAdd(&cnt[ebuf[beg + j] >> 24], 1);
    __syncthreads();
    int v = cnt[t];
    scn[t] = v;
    __syncthreads();
    for (int off = 1; off < 256; off <<= 1) {
        int x = (t >= off) ? scn[t - off] : 0;
        __syncthreads();
        scn[t] += x;
        __syncthreads();
    }
    int excl = scn[t] - v;
    int node = b * 256 + t;
    if (node < N) {
        rs[node]   = beg + excl;
        re[node]   = beg + excl + v;
        dinv[node] = rsqrtf((float)(1 + v));   // +1 self-loop
    }
    cur[t] = beg + excl;
    __syncthreads();
    for (int j = t; j < cntE; j += 256) {
        unsigned e = ebuf[beg + j];
        int pos = atomicAdd(&cur[e >> 24], 1);
        csr[pos] = (int)(e & 0x00FFFFFFu);
    }
}

// ============== weight prep: all 3 weights, bf16 B-frag order ===============
__global__ __launch_bounds__(256) void k_prepW3(const float* __restrict__ W0,
                                                const float* __restrict__ W1,
                                                const float* __restrict__ W2,
                                                unsigned short* __restrict__ Wf) {
    int t = blockIdx.x * 256 + threadIdx.x;   // 0..6143
    int wid = t >> 11;                        // 0,1,2
    int f = t & 2047;
    const float* W = (wid == 0) ? W0 : (wid == 1) ? W1 : W2;
    int C = (wid == 2) ? 40 : 128;
    int lane = f & 63, frag = f >> 6;
    int kt = frag & 3, ct = frag >> 2;
    int r = lane & 15, q = lane >> 4;
    int col = ct * 16 + r;
    int kbase = kt * 32 + q * 8;
    unsigned int v[8];
    #pragma unroll
    for (int j = 0; j < 8; ++j)
        v[j] = (col < C) ? f2bf(W[(size_t)(kbase + j) * C + col]) : 0u;
    uint4 o;
    o.x = v[0] | (v[1] << 16);
    o.y = v[2] | (v[3] << 16);
    o.z = v[4] | (v[5] << 16);
    o.w = v[6] | (v[7] << 16);
    ((uint4*)Wf)[t] = o;
}

// ============================== MFMA GEMM ===================================
__device__ __forceinline__ float bn_apply(float v, int c, const float* stats,
                                          const float* g, const float* be, float invN) {
    float mean = stats[c] * invN;
    float var  = fmaf(-mean, mean, stats[128 + c] * invN);
    float sc   = g[c] * rsqrtf(var + BN_EPS);
    float r    = fmaf(v - mean, sc, be[c]);
    return fmaxf(r, 0.0f);
}

// H[N,OST]_bf16 = bf16( bn_relu(X)[N,128] @ W[:, :NOCT*16] )
template <int NOCT, int OST>
__global__ __launch_bounds__(256) void k_gemm_mfma(
        const void* __restrict__ X, int xf32, const unsigned short* __restrict__ Wf,
        unsigned short* __restrict__ H, int N,
        const float* __restrict__ stats, const float* __restrict__ g,
        const float* __restrict__ be) {
    __shared__ unsigned short aF[16 * 512];
    __shared__ unsigned short bF[NOCT * 4 * 512];
    const int tid = threadIdx.x;
    const int rowbase = blockIdx.x * 64;
    const float invN = 1.0f / (float)N;

    {   // stage B: NOCT col-tiles, lane-contiguous copy
        const uint4* src = (const uint4*)Wf;
        uint4* dst = (uint4*)bF;
        #pragma unroll
        for (int i = 0; i < NOCT; ++i) dst[tid + 256 * i] = src[tid + 256 * i];
    }
    // stage A: one frag-slot per task, BN+ReLU fused
    #pragma unroll
    for (int it = 0; it < 4; ++it) {
        int f = tid + 256 * it;
        int lane = f & 63, frag = f >> 6;
        int kt = frag & 3, rt = frag >> 2;
        int r = lane & 15, q = lane >> 4;
        int row = rowbase + rt * 16 + r;
        int kc = kt * 32 + q * 8;
        float vv[8];
        if (row < N) {
            if (xf32) {
                const float4* xp = (const float4*)((const float*)X + (size_t)row * 128 + kc);
                float4 p0 = xp[0], p1 = xp[1];
                vv[0] = p0.x; vv[1] = p0.y; vv[2] = p0.z; vv[3] = p0.w;
                vv[4] = p1.x; vv[5] = p1.y; vv[6] = p1.z; vv[7] = p1.w;
            } else {
                uint4 p = *((const uint4*)((const unsigned short*)X + (size_t)row * 128 + kc));
                vv[0] = bflo(p.x); vv[1] = bfhi(p.x);
                vv[2] = bflo(p.y); vv[3] = bfhi(p.y);
                vv[4] = bflo(p.z); vv[5] = bfhi(p.z);
                vv[6] = bflo(p.w); vv[7] = bfhi(p.w);
            }
            if (stats) {
                #pragma unroll
                for (int j = 0; j < 8; ++j)
                    vv[j] = bn_apply(vv[j], kc + j, stats, g, be, invN);
            }
        } else {
            #pragma unroll
            for (int j = 0; j < 8; ++j) vv[j] = 0.0f;
        }
        uint4 o;
        o.x = f2bf(vv[0]) | (f2bf(vv[1]) << 16);
        o.y = f2bf(vv[2]) | (f2bf(vv[3]) << 16);
        o.z = f2bf(vv[4]) | (f2bf(vv[5]) << 16);
        o.w = f2bf(vv[6]) | (f2bf(vv[7]) << 16);
        ((uint4*)aF)[f] = o;
    }
    __syncthreads();

    const int wave = tid >> 6, lane = tid & 63;
    f32x4 acc[NOCT];
    #pragma unroll
    for (int ct = 0; ct < NOCT; ++ct) acc[ct] = (f32x4){0.f, 0.f, 0.f, 0.f};

    #pragma unroll
    for (int kt = 0; kt < 4; ++kt) {
        bf16x8 a = ((const bf16x8*)aF)[(wave * 4 + kt) * 64 + lane];
        #pragma unroll
        for (int ct = 0; ct < NOCT; ++ct) {
            bf16x8 b = ((const bf16x8*)bF)[(ct * 4 + kt) * 64 + lane];
            acc[ct] = __builtin_amdgcn_mfma_f32_16x16x32_bf16(a, b, acc[ct], 0, 0, 0);
        }
    }

    const int q = lane >> 4, r = lane & 15;   // C/D: col=lane&15, row=q*4+reg
    #pragma unroll
    for (int ct = 0; ct < NOCT; ++ct) {
        #pragma unroll
        for (int i = 0; i < 4; ++i) {
            int row = rowbase + wave * 16 + q * 4 + i;
            if (row < N)
                H[(size_t)row * OST + ct * 16 + r] = (unsigned short)f2bf(acc[ct][i]);
        }
    }
}

// ========================= gather-based aggregate ===========================
// 16 lanes/node, uint4 (8ch) per lane.
__global__ __launch_bounds__(256) void k_agg128(
        const unsigned short* __restrict__ H, const int* __restrict__ rs,
        const int* __restrict__ re, const int* __restrict__ csr,
        const float* __restrict__ dinv, const float* __restrict__ b,
        unsigned short* __restrict__ outb, int N) {
    int lane = threadIdx.x & 15;
    int node = blockIdx.x * 16 + (threadIdx.x >> 4);
    if (node >= N) return;
    float dd  = dinv[node];
    int   beg = rs[node];
    int   end = re[node];
    uint4 hp  = ((const uint4*)(H + (size_t)node * 128))[lane];
    float4 bb0 = ((const float4*)b)[lane * 2];
    float4 bb1 = ((const float4*)b)[lane * 2 + 1];
    float sl = dd * dd;
    float a0 = fmaf(bflo(hp.x), sl, bb0.x), a1 = fmaf(bfhi(hp.x), sl, bb0.y);
    float a2 = fmaf(bflo(hp.y), sl, bb0.z), a3 = fmaf(bfhi(hp.y), sl, bb0.w);
    float a4 = fmaf(bflo(hp.z), sl, bb1.x), a5 = fmaf(bfhi(hp.z), sl, bb1.y);
    float a6 = fmaf(bflo(hp.w), sl, bb1.z), a7 = fmaf(bfhi(hp.w), sl, bb1.w);
    int j = beg;
    for (; j + 2 <= end; j += 2) {
        int s0 = csr[j], s1 = csr[j + 1];
        float n0 = dinv[s0] * dd, n1 = dinv[s1] * dd;
        uint4 v0 = ((const uint4*)(H + (size_t)s0 * 128))[lane];
        uint4 v1 = ((const uint4*)(H + (size_t)s1 * 128))[lane];
        a0 = fmaf(bflo(v0.x), n0, fmaf(bflo(v1.x), n1, a0));
        a1 = fmaf(bfhi(v0.x), n0, fmaf(bfhi(v1.x), n1, a1));
        a2 = fmaf(bflo(v0.y), n0, fmaf(bflo(v1.y), n1, a2));
        a3 = fmaf(bfhi(v0.y), n0, fmaf(bfhi(v1.y), n1, a3));
        a4 = fmaf(bflo(v0.z), n0, fmaf(bflo(v1.z), n1, a4));
        a5 = fmaf(bfhi(v0.z), n0, fmaf(bfhi(v1.z), n1, a5));
        a6 = fmaf(bflo(v0.w), n0, fmaf(bflo(v1.w), n1, a6));
        a7 = fmaf(bfhi(v0.w), n0, fmaf(bfhi(v1.w), n1, a7));
    }
    if (j < end) {
        int s0 = csr[j];
        float n0 = dinv[s0] * dd;
        uint4 v0 = ((const uint4*)(H + (size_t)s0 * 128))[lane];
        a0 = fmaf(bflo(v0.x), n0, a0); a1 = fmaf(bfhi(v0.x), n0, a1);
        a2 = fmaf(bflo(v0.y), n0, a2); a3 = fmaf(bfhi(v0.y), n0, a3);
        a4 = fmaf(bflo(v0.z), n0, a4); a5 = fmaf(bfhi(v0.z), n0, a5);
        a6 = fmaf(bflo(v0.w), n0, a6); a7 = fmaf(bfhi(v0.w), n0, a7);
    }
    uint4 o;
    o.x = f2bf(a0) | (f2bf(a1) << 16);
    o.y = f2bf(a2) | (f2bf(a3) << 16);
    o.z = f2bf(a4) | (f2bf(a5) << 16);
    o.w = f2bf(a6) | (f2bf(a7) << 16);
    ((uint4*)(outb + (size_t)node * 128))[lane] = o;
}

// 40-ch final from compact stride-48 H
__global__ __launch_bounds__(256) void k_agg40(
        const unsigned short* __restrict__ H, const int* __restrict__ rs,
        const int* __restrict__ re, const int* __restrict__ csr,
        const float* __restrict__ dinv, const float* __restrict__ b,
        float* __restrict__ out, int N) {
    int lane = threadIdx.x & 15;
    int node = blockIdx.x * 16 + (threadIdx.x >> 4);
    if (node >= N || lane >= 10) return;
    float dd  = dinv[node];
    int   beg = rs[node];
    int   end = re[node];
    uint2 hp  = ((const uint2*)(H + (size_t)node * 48))[lane];
    float4 bb = ((const float4*)b)[lane];
    float  sl = dd * dd;
    float4 acc = make_float4(fmaf(bflo(hp.x), sl, bb.x), fmaf(bfhi(hp.x), sl, bb.y),
                             fmaf(bflo(hp.y), sl, bb.z), fmaf(bfhi(hp.y), sl, bb.w));
    int j = beg;
    for (; j + 2 <= end; j += 2) {
        int s0 = csr[j], s1 = csr[j + 1];
        float n0 = dinv[s0] * dd, n1 = dinv[s1] * dd;
        uint2 v0 = ((const uint2*)(H + (size_t)s0 * 48))[lane];
        uint2 v1 = ((const uint2*)(H + (size_t)s1 * 48))[lane];
        acc.x = fmaf(bflo(v0.x), n0, fmaf(bflo(v1.x), n1, acc.x));
        acc.y = fmaf(bfhi(v0.x), n0, fmaf(bfhi(v1.x), n1, acc.y));
        acc.z = fmaf(bflo(v0.y), n0, fmaf(bflo(v1.y), n1, acc.z));
        acc.w = fmaf(bfhi(v0.y), n0, fmaf(bfhi(v1.y), n1, acc.w));
    }
    if (j < end) {
        int s0 = csr[j];
        float n0 = dinv[s0] * dd;
        uint2 v0 = ((const uint2*)(H + (size_t)s0 * 48))[lane];
        acc.x = fmaf(bflo(v0.x), n0, acc.x);
        acc.y = fmaf(bfhi(v0.x), n0, acc.y);
        acc.z = fmaf(bflo(v0.y), n0, acc.z);
        acc.w = fmaf(bfhi(v0.y), n0, acc.w);
    }
    ((float4*)(out + (size_t)node * 40))[lane] = acc;
}

// =============================== BN stats ===================================
// 16 lanes x uint4 per row (8 ch/lane), 2 rows in flight, register partials,
// one uniform LDS reduce per block (uniform work -> barrier harmless).
__global__ __launch_bounds__(256) void k_bnstats(
        const unsigned short* __restrict__ Bb, float* __restrict__ stats, int N) {
    __shared__ float red[2][16][128];
    const int t = threadIdx.x;
    const int lane16 = t & 15, grp = t >> 4;
    const int cbase = lane16 * 8;
    float s[8], q[8];
    #pragma unroll
    for (int k = 0; k < 8; ++k) { s[k] = 0.f; q[k] = 0.f; }

    const int step = gridDim.x * 16;
    for (int r = blockIdx.x * 16 + grp; r < N; r += 2 * step) {
        uint4 p0 = *((const uint4*)(Bb + (size_t)r * 128 + cbase));
        int r1 = r + step;
        if (r1 < N) {
            uint4 p1 = *((const uint4*)(Bb + (size_t)r1 * 128 + cbase));
            float v[8] = {bflo(p1.x), bfhi(p1.x), bflo(p1.y), bfhi(p1.y),
                          bflo(p1.z), bfhi(p1.z), bflo(p1.w), bfhi(p1.w)};
            #pragma unroll
            for (int k = 0; k < 8; ++k) { s[k] += v[k]; q[k] = fmaf(v[k], v[k], q[k]); }
        }
        float u[8] = {bflo(p0.x), bfhi(p0.x), bflo(p0.y), bfhi(p0.y),
                      bflo(p0.z), bfhi(p0.z), bflo(p0.w), bfhi(p0.w)};
        #pragma unroll
        for (int k = 0; k < 8; ++k) { s[k] += u[k]; q[k] = fmaf(u[k], u[k], q[k]); }
    }
    #pragma unroll
    for (int k = 0; k < 8; ++k) {
        red[0][grp][cbase + k] = s[k];
        red[1][grp][cbase + k] = q[k];
    }
    __syncthreads();
    if (t < 128) {
        float acc = 0.f;
        #pragma unroll
        for (int g = 0; g < 16; ++g) acc += red[0][g][t];
        unsafeAtomicAdd(&stats[t], acc);
    } else {
        int c = t - 128;
        float acc = 0.f;
        #pragma unroll
        for (int g = 0; g < 16; ++g) acc += red[1][g][c];
        unsafeAtomicAdd(&stats[128 + c], acc);
    }
}

// ================================ launch ====================================
extern "C" void kernel_launch(void* const* d_in, const int* in_sizes, int n_in,
                              void* d_out, int out_size, void* d_ws, size_t ws_size,
                              hipStream_t stream) {
    const float* x   = (const float*)d_in[0];
    const int*   ei  = (const int*)d_in[1];      // int64 in ref -> int32 from harness
    const float* W0  = (const float*)d_in[2];
    const float* b0  = (const float*)d_in[3];
    const float* g0  = (const float*)d_in[4];
    const float* be0 = (const float*)d_in[5];
    const float* W1  = (const float*)d_in[6];
    const float* b1  = (const float*)d_in[7];
    const float* g1  = (const float*)d_in[8];
    const float* be1 = (const float*)d_in[9];
    const float* W2  = (const float*)d_in[10];
    const float* b2  = (const float*)d_in[11];
    float* out = (float*)d_out;

    const int N  = in_sizes[0] / 128;   // 170000
    const int E  = in_sizes[1] / 2;     // 1200000
    const int NB = (N + 255) >> 8;      // 665 buckets
    const int EB = (E + 8191) / 8192;   // 147 edge-chunk blocks

    // ws layout (4B units)
    float* ws   = (float*)d_ws;
    size_t Npad = ((size_t)N + 511) & ~(size_t)511;
    size_t BCAP = (size_t)NB * CAP;
    float* dinv = ws;
    int*   rs   = (int*)(ws + Npad);
    int*   re   = rs + Npad;
    int*   csr  = re + Npad;                            // BCAP
    unsigned int* ebuf = (unsigned int*)(csr + BCAP);   // BCAP
    int*   bcur = (int*)(ebuf + BCAP);                  // 1024
    float* stats0 = (float*)(bcur + 1024);              // 256
    float* stats1 = stats0 + 256;                       // 256
    unsigned short* Wf = (unsigned short*)(stats1 + 256); // 3*16384 ushort
    unsigned short* Hb = Wf + 3 * 16384;                // Npad*128 bf16
    unsigned short* Bb = Hb + Npad * 128;               // Npad*128 bf16

    // ---- CSR build (4 dispatches, no memsets) ----
    k_init    <<<1, 1024, 0, stream>>>(bcur, stats0, NB);
    k_bscatter<<<EB, 256, 0, stream>>>(ei, bcur, ebuf, E, NB);
    k_bfinal  <<<NB, 256, 0, stream>>>(ebuf, bcur, csr, rs, re, dinv, N);
    k_prepW3  <<<24, 256, 0, stream>>>(W0, W1, W2, Wf);

    int gemm_grid = (N + 63) / 64;
    int agg_grid  = (N + 15) / 16;

    // ---- layer 0 ----
    k_gemm_mfma<8, 128><<<gemm_grid, 256, 0, stream>>>(x, 1, Wf, Hb, N,
                                                       nullptr, nullptr, nullptr);
    k_agg128<<<agg_grid, 256, 0, stream>>>(Hb, rs, re, csr, dinv, b0, Bb, N);
    k_bnstats<<<512, 256, 0, stream>>>(Bb, stats0, N);

    // ---- layer 1 (BN0+ReLU fused into GEMM staging) ----
    k_gemm_mfma<8, 128><<<gemm_grid, 256, 0, stream>>>(Bb, 0, Wf + 16384, Hb, N,
                                                       stats0, g0, be0);
    k_agg128<<<agg_grid, 256, 0, stream>>>(Hb, rs, re, csr, dinv, b1, Bb, N);
    k_bnstats<<<512, 256, 0, stream>>>(Bb, stats1, N);

    // ---- layer 2 (BN1+ReLU fused) -> compact 48-stride H -> 40-ch out ----
    k_gemm_mfma<3, 48><<<gemm_grid, 256, 0, stream>>>(Bb, 0, Wf + 2 * 16384, Hb, N,
                                                      stats1, g1, be1);
    k_agg40<<<agg_grid, 256, 0, stream>>>(Hb, rs, re, csr, dinv, b2, out, N);
}